// Round 7
// baseline (252.628 us; speedup 1.0000x reference)
//
#include <hip/hip_runtime.h>
#include <stdint.h>
#include <math.h>

#define NB 64      // batch
#define BT 512     // time steps
#define NH 768     // hidden
#define NL 9       // labels
#define PBT 528    // padded time rows in crf LDS
#define PADW 772   // padded W row stride (floats): (l*772+h)%32 spreads banks
#define NBB 2      // batches per crf block (2 independent scan chains per wave)

__device__ __forceinline__ float rlane(float v, int i) {
    return __int_as_float(__builtin_amdgcn_readlane(__float_as_int(v), i));
}

// DPP-based cross-lane add: v += dpp_move(v); runs on VALU, NOT the DS pipe.
template<int CTRL, int RM>
__device__ __forceinline__ float dppadd(float v) {
    const int t = __builtin_amdgcn_update_dpp(0, __float_as_int(v), CTRL, RM, 0xf, true);
    return v + __int_as_float(t);
}

// full 64-lane sum -> uniform scalar (read from lane 63)
__device__ __forceinline__ float wave_sum_dpp(float v) {
    v = dppadd<0x111, 0xf>(v);   // row_shr:1
    v = dppadd<0x112, 0xf>(v);   // row_shr:2
    v = dppadd<0x114, 0xf>(v);   // row_shr:4
    v = dppadd<0x118, 0xf>(v);   // row_shr:8  -> lane 15 of each row16 = row sum
    v = dppadd<0x142, 0xa>(v);   // row_bcast:15 into rows 1,3
    v = dppadd<0x143, 0xc>(v);   // row_bcast:31 into rows 2,3 -> lane 63 = total
    return rlane(v, 63);
}

// ---------------------------------------------------------------------------
// Kernel 1: logits = x @ W + b.  (Round-0 verbatim — best verified config.)
// ---------------------------------------------------------------------------
__global__ __launch_bounds__(256, 2) void gemm_kernel(
    const float* __restrict__ x, const float* __restrict__ W,
    const float* __restrict__ bias, float* __restrict__ logits)
{
    __shared__ float wT[NL * PADW];   // 27.8 KB: W transposed [l][h], padded

    const int tid  = threadIdx.x;
    const int lane = tid & 63;

    for (int i = tid; i < NH * NL; i += 256) {
        const int h = i / NL, l = i - h * NL;
        wT[l * PADW + h] = W[i];
    }
    __syncthreads();

    float wr[3][NL][4];
#pragma unroll
    for (int k = 0; k < 3; ++k)
#pragma unroll
        for (int l = 0; l < NL; ++l) {
            const float4 w4 = *(const float4*)&wT[l * PADW + k * 256 + lane * 4];
            wr[k][l][0] = w4.x; wr[k][l][1] = w4.y;
            wr[k][l][2] = w4.z; wr[k][l][3] = w4.w;
        }
    const float bj = bias[lane < NL ? lane : 0];

    const int gwave = (blockIdx.x * blockDim.x + tid) >> 6;
    const int nw    = (gridDim.x * blockDim.x) >> 6;
    const int nrows = NB * BT;
    int row = gwave;
    if (row >= nrows) return;

    const float4* xr = (const float4*)(x + (size_t)row * NH);
    float4 a0 = xr[lane], a1 = xr[64 + lane], a2 = xr[128 + lane];

    while (true) {
        const int nrow = row + nw;
        float4 b0, b1, b2;
        if (nrow < nrows) {   // prefetch next row while computing this one
            const float4* xn = (const float4*)(x + (size_t)nrow * NH);
            b0 = xn[lane]; b1 = xn[64 + lane]; b2 = xn[128 + lane];
        }

        float acc[NL];
#pragma unroll
        for (int l = 0; l < NL; ++l) {
            float s = a0.x * wr[0][l][0];
            s = fmaf(a0.y, wr[0][l][1], s);
            s = fmaf(a0.z, wr[0][l][2], s);
            s = fmaf(a0.w, wr[0][l][3], s);
            s = fmaf(a1.x, wr[1][l][0], s);
            s = fmaf(a1.y, wr[1][l][1], s);
            s = fmaf(a1.z, wr[1][l][2], s);
            s = fmaf(a1.w, wr[1][l][3], s);
            s = fmaf(a2.x, wr[2][l][0], s);
            s = fmaf(a2.y, wr[2][l][1], s);
            s = fmaf(a2.z, wr[2][l][2], s);
            s = fmaf(a2.w, wr[2][l][3], s);
            acc[l] = s;
        }
        float sum[NL];
#pragma unroll
        for (int l = 0; l < NL; ++l) sum[l] = wave_sum_dpp(acc[l]);
        float outv = sum[0];
#pragma unroll
        for (int l = 1; l < NL; ++l) outv = (lane == l) ? sum[l] : outv;
        if (lane < NL) logits[(size_t)row * NL + lane] = outv + bj;

        row = nrow;
        if (row >= nrows) break;
        a0 = b0; a1 = b1; a2 = b2;
    }
}

// ---------------------------------------------------------------------------
// Kernel 2: per-batch CRF.  32 blocks x 256 threads, 2 batches per block.
// THIS ROUND: wave 0 runs logZ for BOTH batches as two interleaved
// independent chains (shared E); wave 1 likewise for viterbi.  The second
// chain's instructions fill the first chain's readlane-hazard/VALU-latency
// stalls -> ~2x scan throughput.  All per-batch arithmetic bit-identical to
// the verified Round-0 code.  Backtrack: Round-0 serial-LDS version (best of
// three tested), one walker per batch on waves 0/1.
// ---------------------------------------------------------------------------
__global__ __launch_bounds__(256) void crf_kernel(
    const float* __restrict__ logits, const float* __restrict__ trans,
    const int* __restrict__ label, const int* __restrict__ seqlen,
    float* __restrict__ vit_out, float* __restrict__ stats)
{
    __shared__ __align__(16) float lg_lds[NBB][PBT * NL];  // zeros past BT
    __shared__ float    val_lds[NBB][BT * NL];             // viterbi alphas
    __shared__ float    trans_lds[NL * NL];
    __shared__ uint8_t  bp_lds[NBB][(BT - 1) * NL];
    __shared__ uint64_t packed_lds[NBB][BT - 1];
    __shared__ uint8_t  vit_lds[NBB][BT];
    __shared__ float    xw[4][4];

    const int tid  = threadIdx.x;
    const int lane = tid & 63;
    const int wv   = tid >> 6;
    const int b0   = blockIdx.x * NBB;          // batches b0, b0+1
    const int sl0  = seqlen[b0];
    const int sl1  = seqlen[b0 + 1];
    const float* lg0 = logits + (size_t)b0 * BT * NL;
    const float* lg1 = lg0 + BT * NL;
    const int j = lane < NL ? lane : 0;

    // stage both batches' logits (float4) + zero padding + transitions
    {
        const float4* s0 = (const float4*)lg0;
        const float4* s1 = (const float4*)lg1;
        float4* d0 = (float4*)&lg_lds[0][0];
        float4* d1 = (float4*)&lg_lds[1][0];
        for (int idx = tid; idx < BT * NL / 4; idx += 256) {
            d0[idx] = s0[idx];
            d1[idx] = s1[idx];
        }
        for (int idx = BT * NL + tid; idx < PBT * NL; idx += 256) {
            lg_lds[0][idx] = 0.f;
            lg_lds[1][idx] = 0.f;
        }
        if (tid < NL * NL) trans_lds[tid] = trans[tid];
    }
    __syncthreads();

    if (wv == 0) {
        // ---- logZ scan, scaled-exp domain: two interleaved chains ----
        float E[NL];
#pragma unroll
        for (int i = 0; i < NL; ++i) E[i] = __expf(trans_lds[i * NL + j]) * 0.125f;
        float A0 = __expf(lg_lds[0][j]);
        float A1 = __expf(lg_lds[1][j]);
        int lc0 = 0, lc1 = 0;
        for (int tb = 1; tb < BT + 8; tb += 8) {
            float P0[8], P1[8];
#pragma unroll
            for (int s = 0; s < 8; ++s) {
                P0[s] = __expf(lg_lds[0][(tb + s) * NL + j]);
                P1[s] = __expf(lg_lds[1][(tb + s) * NL + j]);
            }
#pragma unroll
            for (int s = 0; s < 8; ++s) {
                const int t = tb + s;
                // chain 0
                {
                    const float r0 = rlane(A0, 0), r1 = rlane(A0, 1), r2 = rlane(A0, 2),
                                r3 = rlane(A0, 3), r4 = rlane(A0, 4), r5 = rlane(A0, 5),
                                r6 = rlane(A0, 6), r7 = rlane(A0, 7), r8 = rlane(A0, 8);
                    float p0 = r0 * E[0]; p0 = fmaf(r1, E[1], p0); p0 = fmaf(r2, E[2], p0);
                    float p1 = r3 * E[3]; p1 = fmaf(r4, E[4], p1); p1 = fmaf(r5, E[5], p1);
                    float p2 = r6 * E[6]; p2 = fmaf(r7, E[7], p2); p2 = fmaf(r8, E[8], p2);
                    const float An = ((p0 + p1) + p2) * P0[s];
                    A0 = (t < sl0) ? An : A0;
                }
                // chain 1 (independent: fills chain 0's latency slots)
                {
                    const float r0 = rlane(A1, 0), r1 = rlane(A1, 1), r2 = rlane(A1, 2),
                                r3 = rlane(A1, 3), r4 = rlane(A1, 4), r5 = rlane(A1, 5),
                                r6 = rlane(A1, 6), r7 = rlane(A1, 7), r8 = rlane(A1, 8);
                    float p0 = r0 * E[0]; p0 = fmaf(r1, E[1], p0); p0 = fmaf(r2, E[2], p0);
                    float p1 = r3 * E[3]; p1 = fmaf(r4, E[4], p1); p1 = fmaf(r5, E[5], p1);
                    float p2 = r6 * E[6]; p2 = fmaf(r7, E[7], p2); p2 = fmaf(r8, E[8], p2);
                    const float An = ((p0 + p1) + p2) * P1[s];
                    A1 = (t < sl1) ? An : A1;
                }
            }
            // exact pow2 renorm, per chain (m positive & normal here)
            {
                const float m = fmaxf(fmaxf(
                    fmaxf(fmaxf(rlane(A0, 0), rlane(A0, 1)), fmaxf(rlane(A0, 2), rlane(A0, 3))),
                    fmaxf(fmaxf(rlane(A0, 4), rlane(A0, 5)), fmaxf(rlane(A0, 6), rlane(A0, 7)))),
                    rlane(A0, 8));
                const int ex = (int)((__float_as_uint(m) >> 23) & 0xFFu) - 126;
                const float sc = __uint_as_float((uint32_t)(127 - ex) << 23);
                A0 *= sc;
                lc0 += ex;
            }
            {
                const float m = fmaxf(fmaxf(
                    fmaxf(fmaxf(rlane(A1, 0), rlane(A1, 1)), fmaxf(rlane(A1, 2), rlane(A1, 3))),
                    fmaxf(fmaxf(rlane(A1, 4), rlane(A1, 5)), fmaxf(rlane(A1, 6), rlane(A1, 7)))),
                    rlane(A1, 8));
                const int ex = (int)((__float_as_uint(m) >> 23) & 0xFFu) - 126;
                const float sc = __uint_as_float((uint32_t)(127 - ex) << 23);
                A1 *= sc;
                lc1 += ex;
            }
        }
        const float sum0 = ((rlane(A0, 0) + rlane(A0, 1)) + (rlane(A0, 2) + rlane(A0, 3))) +
                           ((rlane(A0, 4) + rlane(A0, 5)) + (rlane(A0, 6) + rlane(A0, 7))) +
                           rlane(A0, 8);
        const float sum1 = ((rlane(A1, 0) + rlane(A1, 1)) + (rlane(A1, 2) + rlane(A1, 3))) +
                           ((rlane(A1, 4) + rlane(A1, 5)) + (rlane(A1, 6) + rlane(A1, 7))) +
                           rlane(A1, 8);
        const float logZ0 = logf(sum0) +
            ((float)lc0 + 3.0f * (float)(sl0 - 1)) * 0.6931471805599453f;
        const float logZ1 = logf(sum1) +
            ((float)lc1 + 3.0f * (float)(sl1 - 1)) * 0.6931471805599453f;
        if (lane == 0) {
            stats[b0 * 8 + 1]       = logZ0;
            stats[(b0 + 1) * 8 + 1] = logZ1;
        }
    } else if (wv == 1) {
        // ---- viterbi value scans: two interleaved chains ----
        float tc[NL];
#pragma unroll
        for (int i = 0; i < NL; ++i) tc[i] = trans_lds[i * NL + j];
        float v0 = lg_lds[0][j];
        float v1 = lg_lds[1][j];
        if (lane < NL) {
            val_lds[0][j] = v0;
            val_lds[1][j] = v1;
        }
        for (int tb = 1; tb < BT + 8; tb += 8) {
            float lv0[8], lv1[8];
#pragma unroll
            for (int s = 0; s < 8; ++s) {
                lv0[s] = lg_lds[0][(tb + s) * NL + j];
                lv1[s] = lg_lds[1][(tb + s) * NL + j];
            }
#pragma unroll
            for (int s = 0; s < 8; ++s) {
                const int t = tb + s;
                {
                    const float r0 = rlane(v0, 0), r1 = rlane(v0, 1), r2 = rlane(v0, 2),
                                r3 = rlane(v0, 3), r4 = rlane(v0, 4), r5 = rlane(v0, 5),
                                r6 = rlane(v0, 6), r7 = rlane(v0, 7), r8 = rlane(v0, 8);
                    const float c0 = r0 + tc[0], c1 = r1 + tc[1], c2 = r2 + tc[2],
                                c3 = r3 + tc[3], c4 = r4 + tc[4], c5 = r5 + tc[5],
                                c6 = r6 + tc[6], c7 = r7 + tc[7], c8 = r8 + tc[8];
                    const float m = fmaxf(fmaxf(fmaxf(fmaxf(c0, c1), c2),
                                                fmaxf(fmaxf(c3, c4), c5)),
                                          fmaxf(fmaxf(c6, c7), c8));
                    const float nv = m + lv0[s];
                    v0 = (t < sl0) ? nv : v0;
                }
                {
                    const float r0 = rlane(v1, 0), r1 = rlane(v1, 1), r2 = rlane(v1, 2),
                                r3 = rlane(v1, 3), r4 = rlane(v1, 4), r5 = rlane(v1, 5),
                                r6 = rlane(v1, 6), r7 = rlane(v1, 7), r8 = rlane(v1, 8);
                    const float c0 = r0 + tc[0], c1 = r1 + tc[1], c2 = r2 + tc[2],
                                c3 = r3 + tc[3], c4 = r4 + tc[4], c5 = r5 + tc[5],
                                c6 = r6 + tc[6], c7 = r7 + tc[7], c8 = r8 + tc[8];
                    const float m = fmaxf(fmaxf(fmaxf(fmaxf(c0, c1), c2),
                                                fmaxf(fmaxf(c3, c4), c5)),
                                          fmaxf(fmaxf(c6, c7), c8));
                    const float nv = m + lv1[s];
                    v1 = (t < sl1) ? nv : v1;
                }
                if (lane < NL && t < BT) {
                    val_lds[0][t * NL + lane] = v0;
                    val_lds[1][t * NL + lane] = v1;
                }
            }
        }
        // last tag = first-argmax(alphaT), per batch
        {
            const float r0 = rlane(v0, 0), r1 = rlane(v0, 1), r2 = rlane(v0, 2),
                        r3 = rlane(v0, 3), r4 = rlane(v0, 4), r5 = rlane(v0, 5),
                        r6 = rlane(v0, 6), r7 = rlane(v0, 7), r8 = rlane(v0, 8);
            const float m = fmaxf(fmaxf(fmaxf(fmaxf(r0, r1), r2),
                                        fmaxf(fmaxf(r3, r4), r5)),
                                  fmaxf(fmaxf(r6, r7), r8));
            const int last = (r0 == m) ? 0 : (r1 == m) ? 1 : (r2 == m) ? 2 :
                             (r3 == m) ? 3 : (r4 == m) ? 4 : (r5 == m) ? 5 :
                             (r6 == m) ? 6 : (r7 == m) ? 7 : 8;
            if (lane == 0) vit_lds[0][BT - 1] = (uint8_t)last;
        }
        {
            const float r0 = rlane(v1, 0), r1 = rlane(v1, 1), r2 = rlane(v1, 2),
                        r3 = rlane(v1, 3), r4 = rlane(v1, 4), r5 = rlane(v1, 5),
                        r6 = rlane(v1, 6), r7 = rlane(v1, 7), r8 = rlane(v1, 8);
            const float m = fmaxf(fmaxf(fmaxf(fmaxf(r0, r1), r2),
                                        fmaxf(fmaxf(r3, r4), r5)),
                                  fmaxf(fmaxf(r6, r7), r8));
            const int last = (r0 == m) ? 0 : (r1 == m) ? 1 : (r2 == m) ? 2 :
                             (r3 == m) ? 3 : (r4 == m) ? 4 : (r5 == m) ? 5 :
                             (r6 == m) ? 6 : (r7 == m) ? 7 : 8;
            if (lane == 0) vit_lds[1][BT - 1] = (uint8_t)last;
        }
    } else {
        // ---- gold-path score: wave 2 -> batch 0, wave 3 -> batch 1 ----
        const int bb = wv - 2;
        const int sl = bb ? sl1 : sl0;
        const int* lab = label + (size_t)(b0 + bb) * BT;
        float s = 0.f;
        for (int t = lane; t < BT; t += 64) {
            const int lb = lab[t];
            if (t < sl) {
                s += lg_lds[bb][t * NL + lb];
                if (t >= 1) s += trans_lds[lab[t - 1] * NL + lb];
            }
        }
#pragma unroll
        for (int off = 32; off >= 1; off >>= 1) s += __shfl_xor(s, off, 64);
        if (lane == 0) stats[(b0 + bb) * 8 + 0] = s;
    }
    __syncthreads();

    // ---- recompute backpointers in parallel (bit-exact first-max), both ----
    for (int idx = tid; idx < NBB * (BT - 1) * NL; idx += 256) {
        const int bb  = idx / ((BT - 1) * NL);
        const int rem = idx - bb * (BT - 1) * NL;
        const int tm1 = rem / NL;
        const int jj  = rem - tm1 * NL;
        const int t   = tm1 + 1;
        const int sl  = bb ? sl1 : sl0;
        int bi;
        if (t >= sl) bi = jj;
        else {
            float best = val_lds[bb][tm1 * NL] + trans_lds[jj];
            bi = 0;
#pragma unroll
            for (int i = 1; i < NL; ++i) {
                const float c = val_lds[bb][tm1 * NL + i] + trans_lds[i * NL + jj];
                if (c > best) { best = c; bi = i; }
            }
        }
        bp_lds[bb][rem] = (uint8_t)bi;
    }
    __syncthreads();

    // ---- pack bp rows: 9 x 4 bits -> u64, both batches ----
    for (int r = tid; r < NBB * (BT - 1); r += 256) {
        const int bb = r / (BT - 1);
        const int rr = r - bb * (BT - 1);
        uint64_t p = 0;
#pragma unroll
        for (int i = 0; i < NL; ++i)
            p |= (uint64_t)bp_lds[bb][rr * NL + i] << (4 * i);
        packed_lds[bb][rr] = p;
    }
    __syncthreads();

    // ---- serial backtrack (address-independent LDS reads + 2-op extract):
    //      one walker per batch, on different waves -> concurrent ----
    if (lane == 0 && wv < NBB) {
        const int bb = wv;
        int tag = vit_lds[bb][BT - 1];
        for (int t = BT - 2; t >= 0; --t) {
            const uint64_t row = packed_lds[bb][t];
            tag = (int)((row >> (4 * tag)) & 15u);
            vit_lds[bb][t] = (uint8_t)tag;
        }
    }
    __syncthreads();

    // ---- stats + vit output, per batch (xw reused with sync) ----
    for (int bb = 0; bb < NBB; ++bb) {
        const int b  = b0 + bb;
        const int sl = bb ? sl1 : sl0;
        const int* lab = label + (size_t)b * BT;
        float accv = 0.f, tpv = 0.f, tnv = 0.f, fpv = 0.f;
        for (int t = tid; t < BT; t += 256) {
            const int tg = vit_lds[bb][t];
            const int lb = lab[t];
            const bool msk = t < sl;
            vit_out[(size_t)b * BT + t] = (float)tg;
            if (msk && tg == lb) accv += 1.f;
            if (lb > 0 && tg == lb) tpv += 1.f;
            if (lb > 0 && tg != lb) tnv += 1.f;
            if (msk && lb == 0 && tg > 0) fpv += 1.f;
        }
#pragma unroll
        for (int off = 32; off >= 1; off >>= 1) {
            accv += __shfl_xor(accv, off, 64);
            tpv  += __shfl_xor(tpv,  off, 64);
            tnv  += __shfl_xor(tnv,  off, 64);
            fpv  += __shfl_xor(fpv,  off, 64);
        }
        if (lane == 0) { xw[0][wv] = accv; xw[1][wv] = tpv; xw[2][wv] = tnv; xw[3][wv] = fpv; }
        __syncthreads();
        if (tid == 0) {
            stats[b * 8 + 2] = xw[0][0] + xw[0][1] + xw[0][2] + xw[0][3];
            stats[b * 8 + 3] = xw[1][0] + xw[1][1] + xw[1][2] + xw[1][3];
            stats[b * 8 + 4] = xw[2][0] + xw[2][1] + xw[2][2] + xw[2][3];
            stats[b * 8 + 5] = xw[3][0] + xw[3][1] + xw[3][2] + xw[3][3];
        }
        __syncthreads();
    }
}

// ---------------------------------------------------------------------------
// Kernel 3: reduce the 64 per-batch partials -> tp, tn, fp, loss, accuracy
// ---------------------------------------------------------------------------
__global__ __launch_bounds__(64) void finalize_kernel(
    const float* __restrict__ stats, const int* __restrict__ seqlen,
    float* __restrict__ out)
{
    const int lane = threadIdx.x;  // one lane per batch
    float score = stats[lane * 8 + 0];
    float logZ  = stats[lane * 8 + 1];
    float accv  = stats[lane * 8 + 2];
    float tpv   = stats[lane * 8 + 3];
    float tnv   = stats[lane * 8 + 4];
    float fpv   = stats[lane * 8 + 5];
    float nll   = logZ - score;
    float slf   = (float)seqlen[lane];
#pragma unroll
    for (int off = 32; off >= 1; off >>= 1) {
        nll  += __shfl_xor(nll,  off, 64);
        accv += __shfl_xor(accv, off, 64);
        tpv  += __shfl_xor(tpv,  off, 64);
        tnv  += __shfl_xor(tnv,  off, 64);
        fpv  += __shfl_xor(fpv,  off, 64);
        slf  += __shfl_xor(slf,  off, 64);
    }
    if (lane == 0) {
        out[NB * BT + 0] = tpv;
        out[NB * BT + 1] = tnv;
        out[NB * BT + 2] = fpv;
        out[NB * BT + 3] = nll / (float)NB;
        out[NB * BT + 4] = accv / slf;
    }
}

extern "C" void kernel_launch(void* const* d_in, const int* in_sizes, int n_in,
                              void* d_out, int out_size, void* d_ws, size_t ws_size,
                              hipStream_t stream)
{
    const float* x      = (const float*)d_in[0];
    const float* W      = (const float*)d_in[1];
    const float* bias   = (const float*)d_in[2];
    const float* trans  = (const float*)d_in[3];
    const int*   label  = (const int*)d_in[4];
    const int*   seqlen = (const int*)d_in[5];
    // d_in[6] = mask: recomputed from seqlen, unused

    float* out    = (float*)d_out;
    float* logits = (float*)d_ws;                  // 64*512*9 floats
    float* stats  = logits + (size_t)NB * BT * NL; // 64*8 floats

    gemm_kernel<<<512, 256, 0, stream>>>(x, W, bias, logits);
    crf_kernel<<<NB / NBB, 256, 0, stream>>>(logits, trans, label, seqlen, out, stats);
    finalize_kernel<<<1, 64, 0, stream>>>(stats, seqlen, out);
}